// Round 3
// baseline (3142.636 us; speedup 1.0000x reference)
//
#include <hip/hip_runtime.h>
#include <math.h>

#define NTOT  65536
#define DLAT  256
#define KCB   4096
#define CIN   256
#define HWSZ  4096

// workspace float offsets
#define OFF_ZPT   0u            // [256][65536] f32
#define OFF_EMBT  16777216u     // [256][4096]  f32
#define OFF_WT    17825792u     // [256][256]   f32
#define OFF_ENORM 17891328u     // [4096]       f32
#define OFF_RNORM 17895424u     // [65536]      f32
#define OFF_IDX   17960960u     // [65536]      i32
#define OFF_CD    18026496u     // [4][65536]   f32  per-split best dist
#define OFF_CI    18288640u     // [4][65536]   i32  per-split best idx
// total 18550784 floats = 74.2 MB

__global__ __launch_bounds__(256) void wt_kernel(const float* __restrict__ w, float* __restrict__ wT) {
    int t = blockIdx.x * 256 + threadIdx.x;     // 65536
    int o = t >> 8, c = t & 255;
    wT[c * 256 + o] = w[t];
}

__global__ __launch_bounds__(256) void et_kernel(const float* __restrict__ emb, float* __restrict__ embT) {
    int t = blockIdx.x * 256 + threadIdx.x;     // 1048576
    int k = t >> 8, d = t & 255;
    embT[d * KCB + k] = emb[t];
}

__global__ __launch_bounds__(64) void enorm_kernel(const float* __restrict__ emb, float* __restrict__ enorm) {
    int k = blockIdx.x;
    int lane = threadIdx.x;
    double a = 0.0;
    #pragma unroll
    for (int i = 0; i < 4; ++i) {
        float v = emb[k * DLAT + lane + i * 64];
        a = fma((double)v, (double)v, a);
    }
    #pragma unroll
    for (int off = 32; off > 0; off >>= 1) a += __shfl_down(a, off);
    if (lane == 0) enorm[k] = (float)a;   // single rounding to f32
}

__global__ __launch_bounds__(256) void rnorm_kernel(const float* __restrict__ zpT, float* __restrict__ rnorm) {
    int n = blockIdx.x * 256 + threadIdx.x;
    double a = 0.0;
    for (int o = 0; o < DLAT; ++o) {
        float v = zpT[(size_t)o * NTOT + n];
        a = fma((double)v, (double)v, a);
    }
    rnorm[n] = (float)a;                  // single rounding to f32
}

// zpT[o][n] = sum_c z[b][c][hw] * wT[c][o] + bias[o]
__global__ __launch_bounds__(256) void proj_kernel(const float* __restrict__ z, const float* __restrict__ wT,
                                                   const float* __restrict__ bias, float* __restrict__ zpT) {
    __shared__ float zT[16][128];
    __shared__ float wt[16][64];
    int n0 = blockIdx.x * 128;
    int o0 = blockIdx.y * 64;
    int t = threadIdx.x;
    int tm = t & 15, tn = t >> 4;
    int b = n0 >> 12;            // 128 | 4096 -> n-tile stays within one b
    int hw0 = n0 & 4095;
    float acc[8][4] = {};
    for (int c0 = 0; c0 < CIN; c0 += 16) {
        __syncthreads();
        #pragma unroll
        for (int i = 0; i < 2; ++i) {
            int e4 = t + i * 256;               // 0..511 float4 slots (16x128)
            int cc = e4 >> 5, c4 = e4 & 31;
            float4 v = *(const float4*)(z + (size_t)(b * CIN + c0 + cc) * HWSZ + hw0 + c4 * 4);
            *(float4*)&zT[cc][c4 * 4] = v;
        }
        {
            int cc = t >> 4, c4 = t & 15;       // 16x64 = 256 float4 slots
            float4 v = *(const float4*)(wT + (size_t)(c0 + cc) * 256 + o0 + c4 * 4);
            *(float4*)&wt[cc][c4 * 4] = v;
        }
        __syncthreads();
        #pragma unroll
        for (int d = 0; d < 16; ++d) {
            float4 a0 = *(const float4*)&zT[d][tm * 8];
            float4 a1 = *(const float4*)&zT[d][tm * 8 + 4];
            float4 bv = *(const float4*)&wt[d][tn * 4];
            float a[8] = {a0.x,a0.y,a0.z,a0.w,a1.x,a1.y,a1.z,a1.w};
            float bb[4] = {bv.x,bv.y,bv.z,bv.w};
            #pragma unroll
            for (int i = 0; i < 8; ++i)
                #pragma unroll
                for (int j = 0; j < 4; ++j)
                    acc[i][j] = fmaf(a[i], bb[j], acc[i][j]);
        }
    }
    #pragma unroll
    for (int j = 0; j < 4; ++j) {
        int o = o0 + tn * 4 + j;
        float bv = bias[o];
        #pragma unroll
        for (int i = 0; i < 8; ++i) {
            int n = n0 + tm * 8 + i;
            zpT[(size_t)o * NTOT + n] = acc[i][j] + bv;
        }
    }
}

// GEMV-style fused distance + argmin. No LDS, no syncthreads.
// Each wave owns 128 rows (2/lane); B (embT row slices) is wave-uniform ->
// scalar loads into SGPRs. k is split 4-ways across blockIdx.y; per-split
// best (dist,idx) written to cand arrays, merged by merge_kernel.
// Accumulation is bitwise-identical to the verified round-1 kernel:
// 16-d-chunk fmaf partials (init 0) folded into acc in ascending-chunk order.
__global__ __launch_bounds__(256) void argmin_kernel(const float* __restrict__ zpT, const float* __restrict__ embT,
                                                     const float* __restrict__ enorm, const float* __restrict__ rnorm,
                                                     float* __restrict__ cand_d, int* __restrict__ cand_i) {
    const int lane = threadIdx.x & 63;
    const int wv = threadIdx.x >> 6;
    const int row0 = blockIdx.x * 512 + wv * 128 + lane * 2;
    const int s = blockIdx.y;                       // k-split 0..3
    const int ksplit = s * 1024;
    const float2 rnv = *(const float2*)(rnorm + row0);
    const float* __restrict__ ap = zpT + row0;
    float best0 = INFINITY, best1 = INFINITY;
    int bi0 = 0, bi1 = 0;
    for (int p = 0; p < 32; ++p) {                  // 32 codes per pass
        const int kbase = ksplit + p * 32;
        float acc0[32], acc1[32];
        #pragma unroll
        for (int k = 0; k < 32; ++k) { acc0[k] = 0.0f; acc1[k] = 0.0f; }
        for (int d0 = 0; d0 < DLAT; d0 += 16) {
            float c0[32], c1[32];
            #pragma unroll
            for (int k = 0; k < 32; ++k) { c0[k] = 0.0f; c1[k] = 0.0f; }
            #pragma unroll
            for (int dd = 0; dd < 16; ++dd) {
                const int d = d0 + dd;
                const float2 av = *(const float2*)(ap + (size_t)d * NTOT);
                const float* __restrict__ eb = embT + (size_t)d * KCB + kbase;  // wave-uniform
                #pragma unroll
                for (int k = 0; k < 32; ++k) {
                    const float bv = eb[k];         // scalar (SGPR) load
                    c0[k] = fmaf(av.x, bv, c0[k]);
                    c1[k] = fmaf(av.y, bv, c1[k]);
                }
            }
            #pragma unroll
            for (int k = 0; k < 32; ++k) { acc0[k] += c0[k]; acc1[k] += c1[k]; }
        }
        const float* __restrict__ ep = enorm + kbase;  // wave-uniform
        #pragma unroll
        for (int k = 0; k < 32; ++k) {
            const float en = ep[k];
            const float dv0 = (rnv.x - 2.0f * acc0[k]) + en;
            const float dv1 = (rnv.y - 2.0f * acc1[k]) + en;
            const int g = kbase + k;
            if (dv0 < best0) { best0 = dv0; bi0 = g; }   // strict <, ascending k
            if (dv1 < best1) { best1 = dv1; bi1 = g; }
        }
    }
    *(float2*)(cand_d + s * NTOT + row0) = make_float2(best0, best1);
    *(int2*)(cand_i + s * NTOT + row0) = make_int2(bi0, bi1);
}

__global__ __launch_bounds__(256) void merge_kernel(const float* __restrict__ cand_d, const int* __restrict__ cand_i,
                                                    int* __restrict__ idx) {
    int n = blockIdx.x * 256 + threadIdx.x;
    float bv = cand_d[n];
    int bi = cand_i[n];
    #pragma unroll
    for (int s = 1; s < 4; ++s) {
        float v = cand_d[s * NTOT + n];
        int iv = cand_i[s * NTOT + n];
        if (v < bv) { bv = v; bi = iv; }   // strict <: earlier split = lower k wins ties
    }
    idx[n] = bi;
}

// out[b][o][hw] = zp + (emb[idx][o] - zp)   (straight-through, f32-faithful)
__global__ __launch_bounds__(256) void out_kernel(const float* __restrict__ zpT, const float* __restrict__ emb,
                                                  const int* __restrict__ idx, float* __restrict__ out) {
    int e = blockIdx.x * 256 + threadIdx.x;
    int hw = e & 4095;
    int o = (e >> 12) & 255;
    int b = e >> 20;
    int n = (b << 12) | hw;
    float zp = zpT[(size_t)o * NTOT + n];
    float ev = emb[idx[n] * DLAT + o];
    float st = ev - zp;
    out[e] = zp + st;
}

extern "C" void kernel_launch(void* const* d_in, const int* in_sizes, int n_in,
                              void* d_out, int out_size, void* d_ws, size_t ws_size,
                              hipStream_t stream) {
    const float* z    = (const float*)d_in[0];
    const float* w    = (const float*)d_in[1];
    const float* bias = (const float*)d_in[2];
    const float* emb  = (const float*)d_in[3];
    float* ws = (float*)d_ws;
    float* zpT   = ws + OFF_ZPT;
    float* embT  = ws + OFF_EMBT;
    float* wT    = ws + OFF_WT;
    float* enorm = ws + OFF_ENORM;
    float* rnorm = ws + OFF_RNORM;
    int*   idx   = (int*)(ws + OFF_IDX);
    float* cand_d = ws + OFF_CD;
    int*   cand_i = (int*)(ws + OFF_CI);
    float* out   = (float*)d_out;

    hipLaunchKernelGGL(wt_kernel,     dim3(256),      dim3(256), 0, stream, w, wT);
    hipLaunchKernelGGL(et_kernel,     dim3(4096),     dim3(256), 0, stream, emb, embT);
    hipLaunchKernelGGL(enorm_kernel,  dim3(4096),     dim3(64),  0, stream, emb, enorm);
    hipLaunchKernelGGL(proj_kernel,   dim3(512, 4),   dim3(256), 0, stream, z, wT, bias, zpT);
    hipLaunchKernelGGL(rnorm_kernel,  dim3(256),      dim3(256), 0, stream, zpT, rnorm);
    hipLaunchKernelGGL(argmin_kernel, dim3(128, 4),   dim3(256), 0, stream, zpT, embT, enorm, rnorm, cand_d, cand_i);
    hipLaunchKernelGGL(merge_kernel,  dim3(256),      dim3(256), 0, stream, cand_d, cand_i, idx);
    hipLaunchKernelGGL(out_kernel,    dim3(65536),    dim3(256), 0, stream, zpT, emb, idx, out);
}

// Round 4
// 2048.492 us; speedup vs baseline: 1.5341x; 1.5341x over previous
//
#include <hip/hip_runtime.h>
#include <math.h>

#define NTOT  65536
#define DLAT  256
#define KCB   4096
#define CIN   256
#define HWSZ  4096

// workspace float offsets
#define OFF_ZPT   0u            // [256][65536] f32
#define OFF_EMBT  16777216u     // [256][4096]  f32
#define OFF_WT    17825792u     // [256][256]   f32
#define OFF_ENORM 17891328u     // [4096]       f32
#define OFF_RNORM 17895424u     // [65536]      f32
#define OFF_IDX   17960960u     // [65536]      i32
// total 18026496 floats = 72.1 MB

__global__ __launch_bounds__(256) void wt_kernel(const float* __restrict__ w, float* __restrict__ wT) {
    int t = blockIdx.x * 256 + threadIdx.x;     // 65536
    int o = t >> 8, c = t & 255;
    wT[c * 256 + o] = w[t];
}

__global__ __launch_bounds__(256) void et_kernel(const float* __restrict__ emb, float* __restrict__ embT) {
    int t = blockIdx.x * 256 + threadIdx.x;     // 1048576
    int k = t >> 8, d = t & 255;
    embT[d * KCB + k] = emb[t];
}

__global__ __launch_bounds__(64) void enorm_kernel(const float* __restrict__ emb, float* __restrict__ enorm) {
    int k = blockIdx.x;
    int lane = threadIdx.x;
    double a = 0.0;
    #pragma unroll
    for (int i = 0; i < 4; ++i) {
        float v = emb[k * DLAT + lane + i * 64];
        a = fma((double)v, (double)v, a);
    }
    #pragma unroll
    for (int off = 32; off > 0; off >>= 1) a += __shfl_down(a, off);
    if (lane == 0) enorm[k] = (float)a;   // single rounding to f32
}

__global__ __launch_bounds__(256) void rnorm_kernel(const float* __restrict__ zpT, float* __restrict__ rnorm) {
    int n = blockIdx.x * 256 + threadIdx.x;
    double a = 0.0;
    for (int o = 0; o < DLAT; ++o) {
        float v = zpT[(size_t)o * NTOT + n];
        a = fma((double)v, (double)v, a);
    }
    rnorm[n] = (float)a;                  // single rounding to f32
}

// zpT[o][n] = sum_c z[b][c][hw] * wT[c][o] + bias[o]
__global__ __launch_bounds__(256) void proj_kernel(const float* __restrict__ z, const float* __restrict__ wT,
                                                   const float* __restrict__ bias, float* __restrict__ zpT) {
    __shared__ float zT[16][128];
    __shared__ float wt[16][64];
    int n0 = blockIdx.x * 128;
    int o0 = blockIdx.y * 64;
    int t = threadIdx.x;
    int tm = t & 15, tn = t >> 4;
    int b = n0 >> 12;            // 128 | 4096 -> n-tile stays within one b
    int hw0 = n0 & 4095;
    float acc[8][4] = {};
    for (int c0 = 0; c0 < CIN; c0 += 16) {
        __syncthreads();
        #pragma unroll
        for (int i = 0; i < 2; ++i) {
            int e4 = t + i * 256;               // 0..511 float4 slots (16x128)
            int cc = e4 >> 5, c4 = e4 & 31;
            float4 v = *(const float4*)(z + (size_t)(b * CIN + c0 + cc) * HWSZ + hw0 + c4 * 4);
            *(float4*)&zT[cc][c4 * 4] = v;
        }
        {
            int cc = t >> 4, c4 = t & 15;       // 16x64 = 256 float4 slots
            float4 v = *(const float4*)(wT + (size_t)(c0 + cc) * 256 + o0 + c4 * 4);
            *(float4*)&wt[cc][c4 * 4] = v;
        }
        __syncthreads();
        #pragma unroll
        for (int d = 0; d < 16; ++d) {
            float4 a0 = *(const float4*)&zT[d][tm * 8];
            float4 a1 = *(const float4*)&zT[d][tm * 8 + 4];
            float4 bv = *(const float4*)&wt[d][tn * 4];
            float a[8] = {a0.x,a0.y,a0.z,a0.w,a1.x,a1.y,a1.z,a1.w};
            float bb[4] = {bv.x,bv.y,bv.z,bv.w};
            #pragma unroll
            for (int i = 0; i < 8; ++i)
                #pragma unroll
                for (int j = 0; j < 4; ++j)
                    acc[i][j] = fmaf(a[i], bb[j], acc[i][j]);
        }
    }
    #pragma unroll
    for (int j = 0; j < 4; ++j) {
        int o = o0 + tn * 4 + j;
        float bv = bias[o];
        #pragma unroll
        for (int i = 0; i < 8; ++i) {
            int n = n0 + tm * 8 + i;
            zpT[(size_t)o * NTOT + n] = acc[i][j] + bv;
        }
    }
}

// Fused distance + argmin, LDS-tiled, conflict-free fragments.
// Block: 128 rows x 128-code k-steps (32 steps). Thread (tm,tn): 8 rows
// {tm*4+i, 64+tm*4+i} x 8 codes {tn*8+j}. Per d: 2 A-b128 (2-way max) +
// 2 B-b128 (broadcast, 4 addrs/wave) for 64 FMA -> LDS well under VALU.
// Register prefetch (T14): next chunk's 4 float4 loaded during compute.
// Arithmetic per (row,code) is bitwise-identical to the verified round-1
// kernel: 16-d cacc from 0, folded ascending; dist=(rn-2*acc)+en; strict <
// over ascending k per thread; cross-thread merge ties on lower idx.
__global__ __launch_bounds__(256) void argmin_kernel(const float* __restrict__ zpT, const float* __restrict__ embT,
                                                     const float* __restrict__ enorm, const float* __restrict__ rnorm,
                                                     int* __restrict__ idx) {
    __shared__ float zT[16][128];
    __shared__ float eT[16][128];
    __shared__ float rv[128][17];
    __shared__ int   ri[128][17];
    const int t = threadIdx.x;
    const int tm = t & 15, tn = t >> 4;
    const int n0 = blockIdx.x * 128;
    const int sdd0 = t >> 5;             // staging slot row 0..7
    const int sdd1 = sdd0 + 8;
    const int sc0 = (t & 31) * 4;        // staging col (float)

    float rn[8];
    #pragma unroll
    for (int i = 0; i < 4; ++i) {
        rn[i]     = rnorm[n0 + tm * 4 + i];
        rn[4 + i] = rnorm[n0 + 64 + tm * 4 + i];
    }
    float best[8]; int bidx[8];
    #pragma unroll
    for (int i = 0; i < 8; ++i) { best[i] = INFINITY; bidx[i] = 0; }

    float acc[64];
    // prefetch unit 0 (k0=0, d0=0)
    float4 gA0 = *(const float4*)(zpT + (size_t)sdd0 * NTOT + n0 + sc0);
    float4 gA1 = *(const float4*)(zpT + (size_t)sdd1 * NTOT + n0 + sc0);
    float4 gB0 = *(const float4*)(embT + (size_t)sdd0 * KCB + sc0);
    float4 gB1 = *(const float4*)(embT + (size_t)sdd1 * KCB + sc0);

    for (int u = 0; u < 512; ++u) {      // u = step*16 + chunk
        if ((u & 15) == 0) {
            #pragma unroll
            for (int x = 0; x < 64; ++x) acc[x] = 0.0f;
        }
        __syncthreads();
        *(float4*)&zT[sdd0][sc0] = gA0;
        *(float4*)&zT[sdd1][sc0] = gA1;
        *(float4*)&eT[sdd0][sc0] = gB0;
        *(float4*)&eT[sdd1][sc0] = gB1;
        if (u < 511) {                   // issue next chunk's loads (hidden under compute)
            const int un = u + 1;
            const int k0n = (un >> 4) << 7;
            const int d0n = (un & 15) << 4;
            gA0 = *(const float4*)(zpT + (size_t)(d0n + sdd0) * NTOT + n0 + sc0);
            gA1 = *(const float4*)(zpT + (size_t)(d0n + sdd1) * NTOT + n0 + sc0);
            gB0 = *(const float4*)(embT + (size_t)(d0n + sdd0) * KCB + k0n + sc0);
            gB1 = *(const float4*)(embT + (size_t)(d0n + sdd1) * KCB + k0n + sc0);
        }
        __syncthreads();
        float cacc[64];
        #pragma unroll
        for (int x = 0; x < 64; ++x) cacc[x] = 0.0f;
        #pragma unroll
        for (int dd = 0; dd < 16; ++dd) {
            float4 a0 = *(const float4*)&zT[dd][tm * 4];
            float4 a1 = *(const float4*)&zT[dd][64 + tm * 4];
            float4 b0 = *(const float4*)&eT[dd][tn * 8];
            float4 b1 = *(const float4*)&eT[dd][tn * 8 + 4];
            float a[8] = {a0.x,a0.y,a0.z,a0.w,a1.x,a1.y,a1.z,a1.w};
            float b[8] = {b0.x,b0.y,b0.z,b0.w,b1.x,b1.y,b1.z,b1.w};
            #pragma unroll
            for (int i = 0; i < 8; ++i)
                #pragma unroll
                for (int j = 0; j < 8; ++j)
                    cacc[i * 8 + j] = fmaf(a[i], b[j], cacc[i * 8 + j]);
        }
        #pragma unroll
        for (int x = 0; x < 64; ++x) acc[x] += cacc[x];
        if ((u & 15) == 15) {            // epilogue for this k-step
            const int k0 = (u >> 4) << 7;
            #pragma unroll
            for (int j = 0; j < 8; ++j) {
                const int g = k0 + tn * 8 + j;
                const float en = enorm[g];
                #pragma unroll
                for (int i = 0; i < 8; ++i) {
                    const float dv = (rn[i] - 2.0f * acc[i * 8 + j]) + en;
                    if (dv < best[i]) { best[i] = dv; bidx[i] = g; }
                }
            }
        }
    }
    __syncthreads();
    #pragma unroll
    for (int i = 0; i < 4; ++i) {
        rv[tm * 4 + i][tn] = best[i];          ri[tm * 4 + i][tn] = bidx[i];
        rv[64 + tm * 4 + i][tn] = best[4 + i]; ri[64 + tm * 4 + i][tn] = bidx[4 + i];
    }
    __syncthreads();
    if (t < 128) {
        float bv = rv[t][0]; int bi = ri[t][0];
        #pragma unroll
        for (int q = 1; q < 16; ++q) {
            float v = rv[t][q]; int iq = ri[t][q];
            if (v < bv || (v == bv && iq < bi)) { bv = v; bi = iq; }
        }
        idx[n0 + t] = bi;
    }
}

// out[b][o][hw] = zp + (emb[idx][o] - zp)   (straight-through, f32-faithful)
__global__ __launch_bounds__(256) void out_kernel(const float* __restrict__ zpT, const float* __restrict__ emb,
                                                  const int* __restrict__ idx, float* __restrict__ out) {
    int e = blockIdx.x * 256 + threadIdx.x;
    int hw = e & 4095;
    int o = (e >> 12) & 255;
    int b = e >> 20;
    int n = (b << 12) | hw;
    float zp = zpT[(size_t)o * NTOT + n];
    float ev = emb[idx[n] * DLAT + o];
    float st = ev - zp;
    out[e] = zp + st;
}

extern "C" void kernel_launch(void* const* d_in, const int* in_sizes, int n_in,
                              void* d_out, int out_size, void* d_ws, size_t ws_size,
                              hipStream_t stream) {
    const float* z    = (const float*)d_in[0];
    const float* w    = (const float*)d_in[1];
    const float* bias = (const float*)d_in[2];
    const float* emb  = (const float*)d_in[3];
    float* ws = (float*)d_ws;
    float* zpT   = ws + OFF_ZPT;
    float* embT  = ws + OFF_EMBT;
    float* wT    = ws + OFF_WT;
    float* enorm = ws + OFF_ENORM;
    float* rnorm = ws + OFF_RNORM;
    int*   idx   = (int*)(ws + OFF_IDX);
    float* out   = (float*)d_out;

    hipLaunchKernelGGL(wt_kernel,     dim3(256),      dim3(256), 0, stream, w, wT);
    hipLaunchKernelGGL(et_kernel,     dim3(4096),     dim3(256), 0, stream, emb, embT);
    hipLaunchKernelGGL(enorm_kernel,  dim3(4096),     dim3(64),  0, stream, emb, enorm);
    hipLaunchKernelGGL(proj_kernel,   dim3(512, 4),   dim3(256), 0, stream, z, wT, bias, zpT);
    hipLaunchKernelGGL(rnorm_kernel,  dim3(256),      dim3(256), 0, stream, zpT, rnorm);
    hipLaunchKernelGGL(argmin_kernel, dim3(512),      dim3(256), 0, stream, zpT, embT, enorm, rnorm, idx);
    hipLaunchKernelGGL(out_kernel,    dim3(65536),    dim3(256), 0, stream, zpT, emb, idx, out);
}